// Round 6
// baseline (140.122 us; speedup 1.0000x reference)
//
#include <hip/hip_runtime.h>
#include <math.h>

#define NB 8
#define NH 8
#define SEQ 512
#define DK 64
#define NC 5
#define D_IN 262144   // 8*512*64 per batch
#define OUT_SCORE (NB*NH*SEQ*SEQ)   // 16777216
#define PROJ_BLOCKS 128

typedef short short8 __attribute__((ext_vector_type(8)));
typedef float f32x16 __attribute__((ext_vector_type(16)));

// fp32 -> bf16 (RTNE), bit pattern in a short
__device__ __forceinline__ short f2bf(float f) {
  unsigned u = __float_as_uint(f);
  u += 0x7fffu + ((u >> 16) & 1u);
  return (short)(u >> 16);
}
__device__ __forceinline__ short8 pack8(float4 a, float4 b) {
  short8 r;
  r[0] = f2bf(a.x); r[1] = f2bf(a.y); r[2] = f2bf(a.z); r[3] = f2bf(a.w);
  r[4] = f2bf(b.x); r[5] = f2bf(b.y); r[6] = f2bf(b.z); r[7] = f2bf(b.w);
  return r;
}

// ------- Kernel A: proj partials via device atomics + last-block finisher ----
// R6: small_kernel is eliminated. proj blocks atomicAdd their 40 block-sums
// into colsum (ws, memset-zeroed; atomics resolve at the device coherence
// point -> no cross-XCD staleness). The last block to bump the counter
// (rocPRIM pattern) reads colsum via atomic loads (coherent), computes
// softmax/inds/loss and the 5x512 means. Score consumes means across the
// dispatch boundary (HSA release/acquire handles L2 coherence).
// ws layout: cws[0..39] = colsum, ((int*)cws)[40] = counter, means at cws+64.
__global__ __launch_bounds__(256) void proj_kernel(
    const float* __restrict__ K, const float* __restrict__ Wp,
    float* __restrict__ cws, const float* __restrict__ bp,
    const float* __restrict__ Wq, const float* __restrict__ bq,
    const float* __restrict__ Wk, const float* __restrict__ bk,
    float* __restrict__ means, float* __restrict__ loss_out) {
  const float4* Wp4 = (const float4*)Wp;
  float acc[NB][NC];
#pragma unroll
  for (int b = 0; b < NB; ++b)
#pragma unroll
    for (int c = 0; c < NC; ++c) acc[b][c] = 0.f;

#pragma unroll
  for (int it = 0; it < 2; ++it) {
    int i4 = blockIdx.x * 512 + it * 256 + threadIdx.x;  // float4 idx over D_IN
    float w[20];
#pragma unroll
    for (int t = 0; t < 5; ++t) {
      float4 v = Wp4[i4 * 5 + t];
      w[4*t+0] = v.x; w[4*t+1] = v.y; w[4*t+2] = v.z; w[4*t+3] = v.w;
    }
#pragma unroll
    for (int b = 0; b < NB; ++b) {
      float4 kv = ((const float4*)(K + (size_t)b * D_IN))[i4];
      float ke[4] = {kv.x, kv.y, kv.z, kv.w};
#pragma unroll
      for (int e = 0; e < 4; ++e)
#pragma unroll
        for (int c = 0; c < NC; ++c)
          acc[b][c] = fmaf(ke[e], w[5*e + c], acc[b][c]);
    }
  }

  __shared__ float red[4][NB * NC];
  const int tid = threadIdx.x;
  {
    int wave = tid >> 6;
    int lane = tid & 63;
#pragma unroll
    for (int bc = 0; bc < NB * NC; ++bc) {
      float v = acc[bc / NC][bc % NC];
#pragma unroll
      for (int off = 32; off > 0; off >>= 1) v += __shfl_down(v, off);
      if (lane == 0) red[wave][bc] = v;
    }
  }
  __syncthreads();
  if (tid < NB * NC)
    atomicAdd(&cws[tid],
              red[0][tid] + red[1][tid] + red[2][tid] + red[3][tid]);

  __shared__ int lastflag;
  __syncthreads();   // drains vmcnt: colsum atomics complete before counter
  if (tid == 0) {
    unsigned old = atomicAdd((unsigned*)&((int*)cws)[40], 1u);
    lastflag = (old == PROJ_BLOCKS - 1) ? 1 : 0;
  }
  __syncthreads();
  if (!lastflag) return;

  // ---------------- finisher (one block): stats + loss + means ----------
  __shared__ float colsum[NB * NC];
  __shared__ float cq[NB][NC], ckk[NB][NC], ce_sh[NB];
  __shared__ int inds[NB];
  if (tid < NB * NC) colsum[tid] = atomicAdd(&cws[tid], 0.0f);  // coherent read
  __syncthreads();
  if (tid < NB) {
    float cp[NC], zq[NC], zk[NC];
#pragma unroll
    for (int c = 0; c < NC; ++c) cp[c] = colsum[tid * NC + c] + bp[c];
#pragma unroll
    for (int c = 0; c < NC; ++c) { zq[c] = bq[c]; zk[c] = bk[c]; }
#pragma unroll
    for (int j = 0; j < NC; ++j)
#pragma unroll
      for (int c = 0; c < NC; ++c) {
        zq[c] = fmaf(cp[j], Wq[j * NC + c], zq[c]);
        zk[c] = fmaf(cp[j], Wk[j * NC + c], zk[c]);
      }
    float m = zq[0];
#pragma unroll
    for (int c = 1; c < NC; ++c) m = fmaxf(m, zq[c]);
    float e[NC], s = 0.f;
#pragma unroll
    for (int c = 0; c < NC; ++c) { e[c] = expf(zq[c] - m); s += e[c]; }
    float inv = 1.f / s;
    float p[NC];
#pragma unroll
    for (int c = 0; c < NC; ++c) { p[c] = e[c] * inv; cq[tid][c] = p[c]; }
    int am = 0; float bv = p[0];
#pragma unroll
    for (int c = 1; c < NC; ++c) if (p[c] > bv) { bv = p[c]; am = c; }
    inds[tid] = am;
    float se = 0.f;
#pragma unroll
    for (int c = 0; c < NC; ++c) se += expf(p[c] - bv);
    float lse = bv + logf(se);
    float ceb = 0.f;
#pragma unroll
    for (int c = 0; c < NC; ++c) ceb -= p[c] * (p[c] - lse);
    ce_sh[tid] = ceb;
    m = zk[0];
#pragma unroll
    for (int c = 1; c < NC; ++c) m = fmaxf(m, zk[c]);
    s = 0.f;
#pragma unroll
    for (int c = 0; c < NC; ++c) { e[c] = expf(zk[c] - m); s += e[c]; }
    inv = 1.f / s;
#pragma unroll
    for (int c = 0; c < NC; ++c) ckk[tid][c] = e[c] * inv;
  }
  __syncthreads();
  if (tid == 0) {
    float mu[NC];
#pragma unroll
    for (int c = 0; c < NC; ++c) {
      float sm = 0.f;
      for (int b = 0; b < NB; ++b) sm += cq[b][c];
      mu[c] = sm * 0.125f;
    }
    float loss_lp = 0.f;
#pragma unroll
    for (int c = 0; c < NC; ++c) {
      float sm = 0.f;
      for (int b = 0; b < NB; ++b) sm += ckk[b][c];
      float mk = sm * 0.125f;
      float var = 0.f;
      for (int b = 0; b < NB; ++b) {
        float d = ckk[b][c] - mk;
        var += d * d;
      }
      var *= (1.f / 7.f);                 // ddof=1
      float sd = sqrtf(var);
      float sigma = log1pf(expf(sd));     // softplus
      float ls = logf(sigma);
      for (int b = 0; b < NB; ++b) {
        float z = (ckk[b][c] - mu[c]) / sigma;
        loss_lp += -0.5f * z * z - ls - 0.91893853320467274f;
      }
    }
    float ce = 0.f;
    for (int b = 0; b < NB; ++b) ce += ce_sh[b];
    ce *= 0.125f;
    loss_out[0] = -(loss_lp / 40.f) + ce;
  }
  __syncthreads();
  // means[c][j] = (1/8) * sum_{b: inds[b] != c+1} K[b*D_IN + j],  j<512
  // (K is read-only device-wide -> no coherence hazard)
  for (int idx = tid; idx < NC * 512; idx += 256) {
    int c = idx >> 9, j = idx & 511;
    float sm = 0.f;
#pragma unroll
    for (int b = 0; b < NB; ++b)
      if (inds[b] != c + 1) sm += K[(size_t)b * D_IN + j];
    means[idx] = sm * 0.125f;
  }
}

// ---- Kernel C (R0 exact): 128q x 64k tiles, wave = 32q x 64k, 2048 blocks ----
// 32 KB LDS -> 5 blocks/CU = 20 waves/CU. Best-measured score config (~24 us):
// bh-fastest grid, plain scalar stores (2x128B segments/wave-instr), no NT.
#define LDSTRIDE 72   // shorts; 144 B rows: 16B-aligned, uniform b128 bank spread
__global__ __launch_bounds__(256) void score_kernel(const float* __restrict__ Q,
                                                    const float* __restrict__ K,
                                                    const float* __restrict__ means,
                                                    float* __restrict__ out) {
  __shared__ short Qs[128 * LDSTRIDE];       // 18432 B
  __shared__ short Ks[64 * LDSTRIDE];        //  9216 B
  __shared__ float qcbuf[4 * 32 * 10];       //  5120 B  => 32768 B total

  const int bh = blockIdx.x;
  const int h  = bh & 7;
  const int qblk = blockIdx.y << 7;          // 0,128,256,384
  const int kblk = blockIdx.z << 6;          // 0..448 step 64
  const int tid = threadIdx.x;
  const int w = tid >> 6, lane = tid & 63;
  const int lo5 = lane & 31, hi = lane >> 5;
  const int wq = w << 5;                     // wave's q offset in tile (0/32/64/96)

  const float* Qg = Q + (size_t)bh * (SEQ * DK) + (size_t)qblk * DK;
  const float* Kg = K + (size_t)bh * (SEQ * DK) + (size_t)kblk * DK;

  // ---- stage tiles (fp32 -> bf16), coalesced ----
#pragma unroll
  for (int i = 0; i < 4; ++i) {              // Q: 128 rows x 8 chunks
    int f8 = i * 256 + tid;
    int row = f8 >> 3, c8 = f8 & 7;
    const float4* qp = (const float4*)(Qg + row * DK + c8 * 8);
    *(short8*)&Qs[row * LDSTRIDE + c8 * 8] = pack8(qp[0], qp[1]);
  }
#pragma unroll
  for (int i = 0; i < 2; ++i) {              // K: 64 rows x 8 chunks
    int f8 = i * 256 + tid;
    int row = f8 >> 3, c8 = f8 & 7;
    const float4* kp = (const float4*)(Kg + row * DK + c8 * 8);
    *(short8*)&Ks[row * LDSTRIDE + c8 * 8] = pack8(kp[0], kp[1]);
  }

  // ---- means A-fragment (rows 0..7 = cmin, 8..15 = cmax, 16..31 zero) ----
  const int cmin = (5 * h) >> 3;
  const int cmax = (5 * h + 4) >> 3;
  short8 mfrag[4];
#pragma unroll
  for (int s = 0; s < 4; ++s) {
    float4 a = {0.f, 0.f, 0.f, 0.f}, b = {0.f, 0.f, 0.f, 0.f};
    if (lo5 < 16) {
      int c = (lo5 < 8) ? cmin : cmax;
      const float* mp = means + c * 512 + (lo5 & 7) * 64 + s * 16 + hi * 8;
      a = *(const float4*)mp;
      b = *(const float4*)(mp + 4);
    }
    mfrag[s] = pack8(a, b);
  }

  __syncthreads();

  f32x16 zero;
#pragma unroll
  for (int x = 0; x < 16; ++x) zero[x] = 0.f;

  // ---- MFMA loop: 2 acc (k 0-31 / 32-63) + 1 qc per k-step ----
  f32x16 acc0 = zero, acc1 = zero, aq = zero;
#pragma unroll
  for (int s = 0; s < 4; ++s) {
    int co = s * 16 + hi * 8;
    short8 a  = *(const short8*)&Qs[(wq + lo5)  * LDSTRIDE + co];
    short8 b0 = *(const short8*)&Ks[lo5         * LDSTRIDE + co];
    short8 b1 = *(const short8*)&Ks[(32 + lo5)  * LDSTRIDE + co];
    acc0 = __builtin_amdgcn_mfma_f32_32x32x16_bf16(a, b0, acc0, 0, 0, 0);
    acc1 = __builtin_amdgcn_mfma_f32_32x32x16_bf16(a, b1, acc1, 0, 0, 0);
    aq   = __builtin_amdgcn_mfma_f32_32x32x16_bf16(mfrag[s], a, aq, 0, 0, 0);
  }

  // ---- in-lane qc extraction -> wave-private LDS (no barrier needed) ----
  {
    int qb = w * 320 + lo5 * 10 + 4 * hi;
    float2 p;
    p.x = fmaxf(aq[0], aq[4]) * 0.125f;
    p.y = fmaxf(aq[1], aq[5]) * 0.125f;
    *(float2*)&qcbuf[qb] = p;
    p.x = fmaxf(aq[2], aq[6]) * 0.125f;
    p.y = fmaxf(aq[3], aq[7]) * 0.125f;
    *(float2*)&qcbuf[qb + 2] = p;
  }

  // ---- epilogue: qc from LDS (same-wave), plain scalar stores (full lines) ----
  // k = kblk+lo5 and kblk+32+lo5 share (k&7) => same qc for both acc cols.
  float* ob = out + (size_t)bh * (SEQ * SEQ);
  const int kc0 = kblk + lo5;
  const int r = lo5 & 7;
  const int qcb = w * 320 + r;
#pragma unroll
  for (int g = 0; g < 4; ++g) {
#pragma unroll
    for (int e = 0; e < 4; ++e) {
      int reg = 4 * g + e;
      int ql = e + 8 * g + 4 * hi;           // q within wave's 32-row window
      float qc = qcbuf[qcb + ql * 10];
      int qrow = qblk + wq + ql;
      ob[(size_t)qrow * SEQ + kc0]      = fmaxf(acc0[reg] * 0.125f, qc);
      ob[(size_t)qrow * SEQ + kc0 + 32] = fmaxf(acc1[reg] * 0.125f, qc);
    }
  }
}

extern "C" void kernel_launch(void* const* d_in, const int* in_sizes, int n_in,
                              void* d_out, int out_size, void* d_ws, size_t ws_size,
                              hipStream_t stream) {
  const float* Q  = (const float*)d_in[0];
  const float* K  = (const float*)d_in[1];
  const float* Wp = (const float*)d_in[2];
  const float* bp = (const float*)d_in[3];
  const float* Wq = (const float*)d_in[4];
  const float* bq = (const float*)d_in[5];
  const float* Wk = (const float*)d_in[6];
  const float* bk = (const float*)d_in[7];
  float* out = (float*)d_out;

  float* cws   = (float*)d_ws;        // [0..39] colsum, [40] counter (int)
  float* means = cws + 64;            // 5*512 floats, 256B-aligned

  hipMemsetAsync(cws, 0, 41 * sizeof(float), stream);
  proj_kernel<<<PROJ_BLOCKS, 256, 0, stream>>>(K, Wp, cws, bp, Wq, bq, Wk, bk,
                                               means, out + OUT_SCORE);
  score_kernel<<<dim3(64, 4, 8), 256, 0, stream>>>(Q, K, means, out);
}

// Round 7
// 131.465 us; speedup vs baseline: 1.0658x; 1.0658x over previous
//
#include <hip/hip_runtime.h>
#include <math.h>

#define NB 8
#define NH 8
#define SEQ 512
#define DK 64
#define NC 5
#define D_IN 262144   // 8*512*64 per batch
#define OUT_SCORE (NB*NH*SEQ*SEQ)   // 16777216
#define PROJ_BLOCKS 128

typedef short short8 __attribute__((ext_vector_type(8)));
typedef float f32x16 __attribute__((ext_vector_type(16)));

// fp32 -> bf16 via HW packed convert (RTNE, 1 instr per 2 elements).
// Replaces manual integer RTNE (~5 VALU/element): per-thread staging cost
// drops ~450 -> ~40 VALU instrs. No builtin on gfx950 (m240) — inline asm.
__device__ __forceinline__ short8 pack8(float4 a, float4 b) {
  union { short8 s; unsigned u[4]; } r;
  asm("v_cvt_pk_bf16_f32 %0, %1, %2" : "=v"(r.u[0]) : "v"(a.x), "v"(a.y));
  asm("v_cvt_pk_bf16_f32 %0, %1, %2" : "=v"(r.u[1]) : "v"(a.z), "v"(a.w));
  asm("v_cvt_pk_bf16_f32 %0, %1, %2" : "=v"(r.u[2]) : "v"(b.x), "v"(b.y));
  asm("v_cvt_pk_bf16_f32 %0, %1, %2" : "=v"(r.u[3]) : "v"(b.z), "v"(b.w));
  return r.s;
}

// ------- Kernel A: per-block partials of ck[b][c] (proven ~4 us) -------
__global__ __launch_bounds__(256) void proj_kernel(const float* __restrict__ K,
                                                   const float* __restrict__ Wp,
                                                   float* __restrict__ part) {
  const float4* Wp4 = (const float4*)Wp;
  float acc[NB][NC];
#pragma unroll
  for (int b = 0; b < NB; ++b)
#pragma unroll
    for (int c = 0; c < NC; ++c) acc[b][c] = 0.f;

#pragma unroll
  for (int it = 0; it < 2; ++it) {
    int i4 = blockIdx.x * 512 + it * 256 + threadIdx.x;  // float4 idx over D_IN
    float w[20];
#pragma unroll
    for (int t = 0; t < 5; ++t) {
      float4 v = Wp4[i4 * 5 + t];
      w[4*t+0] = v.x; w[4*t+1] = v.y; w[4*t+2] = v.z; w[4*t+3] = v.w;
    }
#pragma unroll
    for (int b = 0; b < NB; ++b) {
      float4 kv = ((const float4*)(K + (size_t)b * D_IN))[i4];
      float ke[4] = {kv.x, kv.y, kv.z, kv.w};
#pragma unroll
      for (int e = 0; e < 4; ++e)
#pragma unroll
        for (int c = 0; c < NC; ++c)
          acc[b][c] = fmaf(ke[e], w[5*e + c], acc[b][c]);
    }
  }

  __shared__ float red[4][NB * NC];
  int wave = threadIdx.x >> 6;
  int lane = threadIdx.x & 63;
#pragma unroll
  for (int bc = 0; bc < NB * NC; ++bc) {
    float v = acc[bc / NC][bc % NC];
#pragma unroll
    for (int off = 32; off > 0; off >>= 1) v += __shfl_down(v, off);
    if (lane == 0) red[wave][bc] = v;
  }
  __syncthreads();
  if (threadIdx.x < NB * NC)
    part[blockIdx.x * (NB * NC) + threadIdx.x] =
        red[0][threadIdx.x] + red[1][threadIdx.x] +
        red[2][threadIdx.x] + red[3][threadIdx.x];
}

// ---- Kernel B (fused): redundant small-phase + 128q x 64k score tiles ----
// R5's exact structure (133.3-pinned config): fused small-phase, R0 grid
// mapping (bh fastest), plain scalar stores. R7 changes ONLY pack8 (above).
#define LDSTRIDE 72   // shorts; 144 B rows: 16B-aligned, uniform b128 bank spread
__global__ __launch_bounds__(256) void score_kernel(
    const float* __restrict__ Q, const float* __restrict__ K,
    const float* __restrict__ part, const float* __restrict__ bp,
    const float* __restrict__ Wq, const float* __restrict__ bq,
    const float* __restrict__ Wk, const float* __restrict__ bk,
    float* __restrict__ out) {
  __shared__ short Qs[128 * LDSTRIDE];       // 18432 B
  __shared__ short Ks[64 * LDSTRIDE];        //  9216 B
  __shared__ __align__(16) float sp[1280];   //  5120 B  => 32768 B total
  // sp union layout:
  //   phase S (small):  means_sh = sp[0..1023]  ([2][512])
  //                     inds     = (int*)&sp[1024] (8)
  //                     cs4      = &sp[1032] ([4][40], row0 doubles as colsum)
  //                     cq       = &sp[1192] ([8][5])
  //                     ckk      = &sp[1232] ([8][5])
  //                     ce       = &sp[1272] (8)
  //   phase E (epilogue): qcbuf = sp[0..1279]  (4 waves x 32 x 10)
  float* means_sh = sp;
  int*   inds_sh  = (int*)&sp[1024];
  float* cs4      = &sp[1032];
  float* cq_sh    = &sp[1192];
  float* ckk_sh   = &sp[1232];
  float* ce_sh    = &sp[1272];

  // R0 grid mapping: bh fastest (blockIdx.x), qblk=y, kblk=z
  const int bh   = blockIdx.x;
  const int qblk = blockIdx.y << 7;          // 0,128,256,384
  const int kblk = blockIdx.z << 6;          // 0..448 step 64
  const int h  = bh & 7;
  const int tid = threadIdx.x;
  const int w = tid >> 6, lane = tid & 63;
  const int lo5 = lane & 31, hi = lane >> 5;
  const int wq = w << 5;                     // wave's q offset in tile (0/32/64/96)

  const float* Qg = Q + (size_t)bh * (SEQ * DK) + (size_t)qblk * DK;
  const float* Kg = K + (size_t)bh * (SEQ * DK) + (size_t)kblk * DK;

  // ---- stage tiles FIRST (fp32 -> bf16): HBM loads issue before small-phase
#pragma unroll
  for (int i = 0; i < 4; ++i) {              // Q: 128 rows x 8 chunks
    int f8 = i * 256 + tid;
    int row = f8 >> 3, c8 = f8 & 7;
    const float4* qp = (const float4*)(Qg + row * DK + c8 * 8);
    *(short8*)&Qs[row * LDSTRIDE + c8 * 8] = pack8(qp[0], qp[1]);
  }
#pragma unroll
  for (int i = 0; i < 2; ++i) {              // K: 64 rows x 8 chunks
    int f8 = i * 256 + tid;
    int row = f8 >> 3, c8 = f8 & 7;
    const float4* kp = (const float4*)(Kg + row * DK + c8 * 8);
    *(short8*)&Ks[row * LDSTRIDE + c8 * 8] = pack8(kp[0], kp[1]);
  }

  // ---- small-phase: colsum of part (L2-warm) -> softmax -> inds/means ----
  if (tid < 160) {
    int sl = tid / 40, c = tid - sl * 40;
    float s = 0.f;
#pragma unroll
    for (int i = 0; i < 32; ++i) s += part[(sl * 32 + i) * (NB * NC) + c];
    cs4[sl * 40 + c] = s;
  }
  __syncthreads();
  if (tid < 40)
    cs4[tid] = cs4[tid] + cs4[40 + tid] + cs4[80 + tid] + cs4[120 + tid];
  __syncthreads();
  if (tid < NB) {
    float cp[NC], zq[NC], zk[NC];
#pragma unroll
    for (int c = 0; c < NC; ++c) cp[c] = cs4[tid * NC + c] + bp[c];
#pragma unroll
    for (int c = 0; c < NC; ++c) { zq[c] = bq[c]; zk[c] = bk[c]; }
#pragma unroll
    for (int j = 0; j < NC; ++j)
#pragma unroll
      for (int c = 0; c < NC; ++c) {
        zq[c] = fmaf(cp[j], Wq[j * NC + c], zq[c]);
        zk[c] = fmaf(cp[j], Wk[j * NC + c], zk[c]);
      }
    float m = zq[0];
#pragma unroll
    for (int c = 1; c < NC; ++c) m = fmaxf(m, zq[c]);
    float e[NC], s = 0.f;
#pragma unroll
    for (int c = 0; c < NC; ++c) { e[c] = expf(zq[c] - m); s += e[c]; }
    float inv = 1.f / s;
    float p[NC];
#pragma unroll
    for (int c = 0; c < NC; ++c) { p[c] = e[c] * inv; cq_sh[tid * NC + c] = p[c]; }
    int am = 0; float bv = p[0];
#pragma unroll
    for (int c = 1; c < NC; ++c) if (p[c] > bv) { bv = p[c]; am = c; }
    inds_sh[tid] = am;
    float se = 0.f;
#pragma unroll
    for (int c = 0; c < NC; ++c) se += expf(p[c] - bv);
    float lse = bv + logf(se);
    float ceb = 0.f;
#pragma unroll
    for (int c = 0; c < NC; ++c) ceb -= p[c] * (p[c] - lse);
    ce_sh[tid] = ceb;
    m = zk[0];
#pragma unroll
    for (int c = 1; c < NC; ++c) m = fmaxf(m, zk[c]);
    s = 0.f;
#pragma unroll
    for (int c = 0; c < NC; ++c) { e[c] = expf(zk[c] - m); s += e[c]; }
    inv = 1.f / s;
#pragma unroll
    for (int c = 0; c < NC; ++c) ckk_sh[tid * NC + c] = e[c] * inv;
  }
  __syncthreads();

  // ---- loss: block (bh=0,qblk=0,kblk=0) thread 0 only ----
  if (blockIdx.x == 0 && blockIdx.y == 0 && blockIdx.z == 0 && tid == 0) {
    float mu[NC];
#pragma unroll
    for (int c = 0; c < NC; ++c) {
      float sm = 0.f;
      for (int b = 0; b < NB; ++b) sm += cq_sh[b * NC + c];
      mu[c] = sm * 0.125f;
    }
    float loss_lp = 0.f;
#pragma unroll
    for (int c = 0; c < NC; ++c) {
      float sm = 0.f;
      for (int b = 0; b < NB; ++b) sm += ckk_sh[b * NC + c];
      float mk = sm * 0.125f;
      float var = 0.f;
      for (int b = 0; b < NB; ++b) {
        float d = ckk_sh[b * NC + c] - mk;
        var += d * d;
      }
      var *= (1.f / 7.f);                 // ddof=1
      float sd = sqrtf(var);
      float sigma = log1pf(expf(sd));     // softplus
      float ls = logf(sigma);
      for (int b = 0; b < NB; ++b) {
        float z = (ckk_sh[b * NC + c] - mu[c]) / sigma;
        loss_lp += -0.5f * z * z - ls - 0.91893853320467274f;
      }
    }
    float ce = 0.f;
    for (int b = 0; b < NB; ++b) ce += ce_sh[b];
    ce *= 0.125f;
    out[OUT_SCORE] = -(loss_lp / 40.f) + ce;
  }

  // ---- means slice for this head's 2 clusters (K rows are L2/L3-hot) ----
  const int cmin = (5 * h) >> 3;
  const int cmax = (5 * h + 4) >> 3;
  for (int idx = tid; idx < 2 * 512; idx += 256) {
    int c2 = idx >> 9, j = idx & 511;
    int c = c2 ? cmax : cmin;
    float sm = 0.f;
#pragma unroll
    for (int b = 0; b < NB; ++b)
      if (inds_sh[b] != c + 1) sm += K[(size_t)b * D_IN + j];
    means_sh[idx] = sm * 0.125f;
  }
  __syncthreads();

  // ---- means A-fragment (rows 0..7 = cmin, 8..15 = cmax, 16..31 zero) ----
  short8 mfrag[4];
#pragma unroll
  for (int s = 0; s < 4; ++s) {
    float4 a = {0.f, 0.f, 0.f, 0.f}, b = {0.f, 0.f, 0.f, 0.f};
    if (lo5 < 16) {
      const float* mp = means_sh + (lo5 >> 3 << 9) + (lo5 & 7) * 64 + s * 16 + hi * 8;
      a = *(const float4*)mp;
      b = *(const float4*)(mp + 4);
    }
    mfrag[s] = pack8(a, b);
  }

  __syncthreads();   // mfrag/means reads done; qcbuf may now overwrite sp

  f32x16 zero;
#pragma unroll
  for (int x = 0; x < 16; ++x) zero[x] = 0.f;

  // ---- MFMA loop: 2 acc (k 0-31 / 32-63) + 1 qc per k-step ----
  f32x16 acc0 = zero, acc1 = zero, aq = zero;
#pragma unroll
  for (int s = 0; s < 4; ++s) {
    int co = s * 16 + hi * 8;
    short8 a  = *(const short8*)&Qs[(wq + lo5)  * LDSTRIDE + co];
    short8 b0 = *(const short8*)&Ks[lo5         * LDSTRIDE + co];
    short8 b1 = *(const short8*)&Ks[(32 + lo5)  * LDSTRIDE + co];
    acc0 = __builtin_amdgcn_mfma_f32_32x32x16_bf16(a, b0, acc0, 0, 0, 0);
    acc1 = __builtin_amdgcn_mfma_f32_32x32x16_bf16(a, b1, acc1, 0, 0, 0);
    aq   = __builtin_amdgcn_mfma_f32_32x32x16_bf16(mfrag[s], a, aq, 0, 0, 0);
  }

  // ---- in-lane qc extraction -> wave-private LDS (no barrier needed) ----
  float* qcbuf = sp;
  {
    int qb = w * 320 + lo5 * 10 + 4 * hi;
    float2 p;
    p.x = fmaxf(aq[0], aq[4]) * 0.125f;
    p.y = fmaxf(aq[1], aq[5]) * 0.125f;
    *(float2*)&qcbuf[qb] = p;
    p.x = fmaxf(aq[2], aq[6]) * 0.125f;
    p.y = fmaxf(aq[3], aq[7]) * 0.125f;
    *(float2*)&qcbuf[qb + 2] = p;
  }

  // ---- epilogue: qc from LDS (same-wave), plain scalar stores (full lines) ----
  // k = kblk+lo5 and kblk+32+lo5 share (k&7) => same qc for both acc cols.
  float* ob = out + (size_t)bh * (SEQ * SEQ);
  const int kc0 = kblk + lo5;
  const int r = lo5 & 7;
  const int qcb = w * 320 + r;
#pragma unroll
  for (int g = 0; g < 4; ++g) {
#pragma unroll
    for (int e = 0; e < 4; ++e) {
      int reg = 4 * g + e;
      int ql = e + 8 * g + 4 * hi;           // q within wave's 32-row window
      float qc = qcbuf[qcb + ql * 10];
      int qrow = qblk + wq + ql;
      ob[(size_t)qrow * SEQ + kc0]      = fmaxf(acc0[reg] * 0.125f, qc);
      ob[(size_t)qrow * SEQ + kc0 + 32] = fmaxf(acc1[reg] * 0.125f, qc);
    }
  }
}

extern "C" void kernel_launch(void* const* d_in, const int* in_sizes, int n_in,
                              void* d_out, int out_size, void* d_ws, size_t ws_size,
                              hipStream_t stream) {
  const float* Q  = (const float*)d_in[0];
  const float* K  = (const float*)d_in[1];
  const float* Wp = (const float*)d_in[2];
  const float* bp = (const float*)d_in[3];
  const float* Wq = (const float*)d_in[4];
  const float* bq = (const float*)d_in[5];
  const float* Wk = (const float*)d_in[6];
  const float* bk = (const float*)d_in[7];
  float* out = (float*)d_out;

  float* part = (float*)d_ws;                      // 128*40 partials

  proj_kernel<<<PROJ_BLOCKS, 256, 0, stream>>>(K, Wp, part);
  score_kernel<<<dim3(64, 4, 8), 256, 0, stream>>>(Q, K, part, bp, Wq, bq, Wk, bk, out);
}

// Round 8
// 124.901 us; speedup vs baseline: 1.1219x; 1.0526x over previous
//
#include <hip/hip_runtime.h>
#include <math.h>

#define NB 8
#define NH 8
#define SEQ 512
#define DK 64
#define NC 5
#define D_IN 262144   // 8*512*64 per batch
#define OUT_SCORE (NB*NH*SEQ*SEQ)   // 16777216
#define PROJ_BLOCKS 128

typedef short short8 __attribute__((ext_vector_type(8)));
typedef float f32x16 __attribute__((ext_vector_type(16)));

// fp32 -> bf16 via HW packed convert (RTNE, 1 instr per 2 elements). R7 win.
__device__ __forceinline__ short8 pack8(float4 a, float4 b) {
  union { short8 s; unsigned u[4]; } r;
  asm("v_cvt_pk_bf16_f32 %0, %1, %2" : "=v"(r.u[0]) : "v"(a.x), "v"(a.y));
  asm("v_cvt_pk_bf16_f32 %0, %1, %2" : "=v"(r.u[1]) : "v"(a.z), "v"(a.w));
  asm("v_cvt_pk_bf16_f32 %0, %1, %2" : "=v"(r.u[2]) : "v"(b.x), "v"(b.y));
  asm("v_cvt_pk_bf16_f32 %0, %1, %2" : "=v"(r.u[3]) : "v"(b.z), "v"(b.w));
  return r.s;
}

// ------- Kernel A: per-block partials of ck[b][c] (proven ~4 us) -------
// R8: part is written TRANSPOSED (part[col][block], col-major 512B columns)
// so score's redundant colsum can read each column with coalesced float4s.
__global__ __launch_bounds__(256) void proj_kernel(const float* __restrict__ K,
                                                   const float* __restrict__ Wp,
                                                   float* __restrict__ part) {
  const float4* Wp4 = (const float4*)Wp;
  float acc[NB][NC];
#pragma unroll
  for (int b = 0; b < NB; ++b)
#pragma unroll
    for (int c = 0; c < NC; ++c) acc[b][c] = 0.f;

#pragma unroll
  for (int it = 0; it < 2; ++it) {
    int i4 = blockIdx.x * 512 + it * 256 + threadIdx.x;  // float4 idx over D_IN
    float w[20];
#pragma unroll
    for (int t = 0; t < 5; ++t) {
      float4 v = Wp4[i4 * 5 + t];
      w[4*t+0] = v.x; w[4*t+1] = v.y; w[4*t+2] = v.z; w[4*t+3] = v.w;
    }
#pragma unroll
    for (int b = 0; b < NB; ++b) {
      float4 kv = ((const float4*)(K + (size_t)b * D_IN))[i4];
      float ke[4] = {kv.x, kv.y, kv.z, kv.w};
#pragma unroll
      for (int e = 0; e < 4; ++e)
#pragma unroll
        for (int c = 0; c < NC; ++c)
          acc[b][c] = fmaf(ke[e], w[5*e + c], acc[b][c]);
    }
  }

  __shared__ float red[4][NB * NC];
  int wave = threadIdx.x >> 6;
  int lane = threadIdx.x & 63;
#pragma unroll
  for (int bc = 0; bc < NB * NC; ++bc) {
    float v = acc[bc / NC][bc % NC];
#pragma unroll
    for (int off = 32; off > 0; off >>= 1) v += __shfl_down(v, off);
    if (lane == 0) red[wave][bc] = v;
  }
  __syncthreads();
  if (threadIdx.x < NB * NC)
    part[threadIdx.x * PROJ_BLOCKS + blockIdx.x] =     // transposed
        red[0][threadIdx.x] + red[1][threadIdx.x] +
        red[2][threadIdx.x] + red[3][threadIdx.x];
}

// ---- Kernel B (fused): redundant small-phase + 128q x 64k score tiles ----
// R7 base (131.5us) + R8: vectorized small-phase loads. colsum: 4 thr/col x
// 8 float4 (column-contiguous via transposed part). means: 1 float4/thread,
// 8 masked float4 accumulates (replaces 32 scalar loads/thread in each).
#define LDSTRIDE 72   // shorts; 144 B rows: 16B-aligned, uniform b128 bank spread
__global__ __launch_bounds__(256) void score_kernel(
    const float* __restrict__ Q, const float* __restrict__ K,
    const float* __restrict__ part, const float* __restrict__ bp,
    const float* __restrict__ Wq, const float* __restrict__ bq,
    const float* __restrict__ Wk, const float* __restrict__ bk,
    float* __restrict__ out) {
  __shared__ short Qs[128 * LDSTRIDE];       // 18432 B
  __shared__ short Ks[64 * LDSTRIDE];        //  9216 B
  __shared__ __align__(16) float sp[1280];   //  5120 B  => 32768 B total
  float* means_sh = sp;                      // [2][512]
  int*   inds_sh  = (int*)&sp[1024];         // 8
  float* cs4      = &sp[1032];               // [4][40]
  float* cq_sh    = &sp[1192];               // [8][5]
  float* ckk_sh   = &sp[1232];               // [8][5]
  float* ce_sh    = &sp[1272];               // 8

  // R0 grid mapping: bh fastest (blockIdx.x), qblk=y, kblk=z
  const int bh   = blockIdx.x;
  const int qblk = blockIdx.y << 7;          // 0,128,256,384
  const int kblk = blockIdx.z << 6;          // 0..448 step 64
  const int h  = bh & 7;
  const int tid = threadIdx.x;
  const int w = tid >> 6, lane = tid & 63;
  const int lo5 = lane & 31, hi = lane >> 5;
  const int wq = w << 5;                     // wave's q offset in tile (0/32/64/96)

  const float* Qg = Q + (size_t)bh * (SEQ * DK) + (size_t)qblk * DK;
  const float* Kg = K + (size_t)bh * (SEQ * DK) + (size_t)kblk * DK;

  // ---- stage tiles FIRST (fp32 -> bf16): HBM loads issue before small-phase
#pragma unroll
  for (int i = 0; i < 4; ++i) {              // Q: 128 rows x 8 chunks
    int f8 = i * 256 + tid;
    int row = f8 >> 3, c8 = f8 & 7;
    const float4* qp = (const float4*)(Qg + row * DK + c8 * 8);
    *(short8*)&Qs[row * LDSTRIDE + c8 * 8] = pack8(qp[0], qp[1]);
  }
#pragma unroll
  for (int i = 0; i < 2; ++i) {              // K: 64 rows x 8 chunks
    int f8 = i * 256 + tid;
    int row = f8 >> 3, c8 = f8 & 7;
    const float4* kp = (const float4*)(Kg + row * DK + c8 * 8);
    *(short8*)&Ks[row * LDSTRIDE + c8 * 8] = pack8(kp[0], kp[1]);
  }

  // ---- small-phase: vectorized colsum (transposed part) -> softmax ----
  if (tid < 160) {
    int col = tid >> 2, sub = tid & 3;       // 40 cols x 4 threads
    const float4* p4 = (const float4*)part + col * 32 + sub * 8;
    float4 s4 = {0.f, 0.f, 0.f, 0.f};
#pragma unroll
    for (int i = 0; i < 8; ++i) {
      float4 v = p4[i];
      s4.x += v.x; s4.y += v.y; s4.z += v.z; s4.w += v.w;
    }
    cs4[sub * 40 + col] = (s4.x + s4.y) + (s4.z + s4.w);
  }
  __syncthreads();
  if (tid < 40)
    cs4[tid] = cs4[tid] + cs4[40 + tid] + cs4[80 + tid] + cs4[120 + tid];
  __syncthreads();
  if (tid < NB) {
    float cp[NC], zq[NC], zk[NC];
#pragma unroll
    for (int c = 0; c < NC; ++c) cp[c] = cs4[tid * NC + c] + bp[c];
#pragma unroll
    for (int c = 0; c < NC; ++c) { zq[c] = bq[c]; zk[c] = bk[c]; }
#pragma unroll
    for (int j = 0; j < NC; ++j)
#pragma unroll
      for (int c = 0; c < NC; ++c) {
        zq[c] = fmaf(cp[j], Wq[j * NC + c], zq[c]);
        zk[c] = fmaf(cp[j], Wk[j * NC + c], zk[c]);
      }
    float m = zq[0];
#pragma unroll
    for (int c = 1; c < NC; ++c) m = fmaxf(m, zq[c]);
    float e[NC], s = 0.f;
#pragma unroll
    for (int c = 0; c < NC; ++c) { e[c] = expf(zq[c] - m); s += e[c]; }
    float inv = 1.f / s;
    float p[NC];
#pragma unroll
    for (int c = 0; c < NC; ++c) { p[c] = e[c] * inv; cq_sh[tid * NC + c] = p[c]; }
    int am = 0; float bv = p[0];
#pragma unroll
    for (int c = 1; c < NC; ++c) if (p[c] > bv) { bv = p[c]; am = c; }
    inds_sh[tid] = am;
    float se = 0.f;
#pragma unroll
    for (int c = 0; c < NC; ++c) se += expf(p[c] - bv);
    float lse = bv + logf(se);
    float ceb = 0.f;
#pragma unroll
    for (int c = 0; c < NC; ++c) ceb -= p[c] * (p[c] - lse);
    ce_sh[tid] = ceb;
    m = zk[0];
#pragma unroll
    for (int c = 1; c < NC; ++c) m = fmaxf(m, zk[c]);
    s = 0.f;
#pragma unroll
    for (int c = 0; c < NC; ++c) { e[c] = expf(zk[c] - m); s += e[c]; }
    inv = 1.f / s;
#pragma unroll
    for (int c = 0; c < NC; ++c) ckk_sh[tid * NC + c] = e[c] * inv;
  }
  __syncthreads();

  // ---- loss: block (0,0,0) thread 0 only ----
  if (blockIdx.x == 0 && blockIdx.y == 0 && blockIdx.z == 0 && tid == 0) {
    float mu[NC];
#pragma unroll
    for (int c = 0; c < NC; ++c) {
      float sm = 0.f;
      for (int b = 0; b < NB; ++b) sm += cq_sh[b * NC + c];
      mu[c] = sm * 0.125f;
    }
    float loss_lp = 0.f;
#pragma unroll
    for (int c = 0; c < NC; ++c) {
      float sm = 0.f;
      for (int b = 0; b < NB; ++b) sm += ckk_sh[b * NC + c];
      float mk = sm * 0.125f;
      float var = 0.f;
      for (int b = 0; b < NB; ++b) {
        float d = ckk_sh[b * NC + c] - mk;
        var += d * d;
      }
      var *= (1.f / 7.f);                 // ddof=1
      float sd = sqrtf(var);
      float sigma = log1pf(expf(sd));     // softplus
      float ls = logf(sigma);
      for (int b = 0; b < NB; ++b) {
        float z = (ckk_sh[b * NC + c] - mu[c]) / sigma;
        loss_lp += -0.5f * z * z - ls - 0.91893853320467274f;
      }
    }
    float ce = 0.f;
    for (int b = 0; b < NB; ++b) ce += ce_sh[b];
    ce *= 0.125f;
    out[OUT_SCORE] = -(loss_lp / 40.f) + ce;
  }

  // ---- means slice: 1 float4/thread, 8 masked float4 accumulates ----
  const int cmin = (5 * h) >> 3;
  const int cmax = (5 * h + 4) >> 3;
  {
    int c2 = tid >> 7;                       // 0 or 1
    int c  = c2 ? cmax : cmin;
    int j4 = (tid & 127) << 2;               // j in steps of 4
    float4 sm = {0.f, 0.f, 0.f, 0.f};
#pragma unroll
    for (int b = 0; b < NB; ++b) {
      if (inds_sh[b] != c + 1) {
        float4 kv = *(const float4*)(K + (size_t)b * D_IN + j4);
        sm.x += kv.x; sm.y += kv.y; sm.z += kv.z; sm.w += kv.w;
      }
    }
    sm.x *= 0.125f; sm.y *= 0.125f; sm.z *= 0.125f; sm.w *= 0.125f;
    *(float4*)&means_sh[c2 * 512 + j4] = sm;
  }
  __syncthreads();

  // ---- means A-fragment (rows 0..7 = cmin, 8..15 = cmax, 16..31 zero) ----
  short8 mfrag[4];
#pragma unroll
  for (int s = 0; s < 4; ++s) {
    float4 a = {0.f, 0.f, 0.f, 0.f}, b = {0.f, 0.f, 0.f, 0.f};
    if (lo5 < 16) {
      const float* mp = means_sh + (lo5 >> 3 << 9) + (lo5 & 7) * 64 + s * 16 + hi * 8;
      a = *(const float4*)mp;
      b = *(const float4*)(mp + 4);
    }
    mfrag[s] = pack8(a, b);
  }

  __syncthreads();   // mfrag/means reads done; qcbuf may now overwrite sp

  f32x16 zero;
#pragma unroll
  for (int x = 0; x < 16; ++x) zero[x] = 0.f;

  // ---- MFMA loop: 2 acc (k 0-31 / 32-63) + 1 qc per k-step ----
  f32x16 acc0 = zero, acc1 = zero, aq = zero;
#pragma unroll
  for (int s = 0; s < 4; ++s) {
    int co = s * 16 + hi * 8;
    short8 a  = *(const short8*)&Qs[(wq + lo5)  * LDSTRIDE + co];
    short8 b0 = *(const short8*)&Ks[lo5         * LDSTRIDE + co];
    short8 b1 = *(const short8*)&Ks[(32 + lo5)  * LDSTRIDE + co];
    acc0 = __builtin_amdgcn_mfma_f32_32x32x16_bf16(a, b0, acc0, 0, 0, 0);
    acc1 = __builtin_amdgcn_mfma_f32_32x32x16_bf16(a, b1, acc1, 0, 0, 0);
    aq   = __builtin_amdgcn_mfma_f32_32x32x16_bf16(mfrag[s], a, aq, 0, 0, 0);
  }

  // ---- in-lane qc extraction -> wave-private LDS (no barrier needed) ----
  float* qcbuf = sp;
  {
    int qb = w * 320 + lo5 * 10 + 4 * hi;
    float2 p;
    p.x = fmaxf(aq[0], aq[4]) * 0.125f;
    p.y = fmaxf(aq[1], aq[5]) * 0.125f;
    *(float2*)&qcbuf[qb] = p;
    p.x = fmaxf(aq[2], aq[6]) * 0.125f;
    p.y = fmaxf(aq[3], aq[7]) * 0.125f;
    *(float2*)&qcbuf[qb + 2] = p;
  }

  // ---- epilogue: qc from LDS (same-wave), plain scalar stores (full lines) ----
  // k = kblk+lo5 and kblk+32+lo5 share (k&7) => same qc for both acc cols.
  float* ob = out + (size_t)bh * (SEQ * SEQ);
  const int kc0 = kblk + lo5;
  const int r = lo5 & 7;
  const int qcb = w * 320 + r;
#pragma unroll
  for (int g = 0; g < 4; ++g) {
#pragma unroll
    for (int e = 0; e < 4; ++e) {
      int reg = 4 * g + e;
      int ql = e + 8 * g + 4 * hi;           // q within wave's 32-row window
      float qc = qcbuf[qcb + ql * 10];
      int qrow = qblk + wq + ql;
      ob[(size_t)qrow * SEQ + kc0]      = fmaxf(acc0[reg] * 0.125f, qc);
      ob[(size_t)qrow * SEQ + kc0 + 32] = fmaxf(acc1[reg] * 0.125f, qc);
    }
  }
}

extern "C" void kernel_launch(void* const* d_in, const int* in_sizes, int n_in,
                              void* d_out, int out_size, void* d_ws, size_t ws_size,
                              hipStream_t stream) {
  const float* Q  = (const float*)d_in[0];
  const float* K  = (const float*)d_in[1];
  const float* Wp = (const float*)d_in[2];
  const float* bp = (const float*)d_in[3];
  const float* Wq = (const float*)d_in[4];
  const float* bq = (const float*)d_in[5];
  const float* Wk = (const float*)d_in[6];
  const float* bk = (const float*)d_in[7];
  float* out = (float*)d_out;

  float* part = (float*)d_ws;                      // 40 cols x 128 (transposed)

  proj_kernel<<<PROJ_BLOCKS, 256, 0, stream>>>(K, Wp, part);
  score_kernel<<<dim3(64, 4, 8), 256, 0, stream>>>(Q, K, part, bp, Wq, bq, Wk, bk, out);
}

// Round 9
// 119.568 us; speedup vs baseline: 1.1719x; 1.0446x over previous
//
#include <hip/hip_runtime.h>
#include <math.h>

#define NB 8
#define NH 8
#define SEQ 512
#define DK 64
#define NC 5
#define D_IN 262144   // 8*512*64 per batch
#define OUT_SCORE (NB*NH*SEQ*SEQ)   // 16777216
#define PROJ_BLOCKS 128

typedef short short8 __attribute__((ext_vector_type(8)));
typedef float f32x16 __attribute__((ext_vector_type(16)));

// fp32 -> bf16 via HW packed convert (RTNE, 1 instr per 2 elements). R7 win.
__device__ __forceinline__ short8 pack8(float4 a, float4 b) {
  union { short8 s; unsigned u[4]; } r;
  asm("v_cvt_pk_bf16_f32 %0, %1, %2" : "=v"(r.u[0]) : "v"(a.x), "v"(a.y));
  asm("v_cvt_pk_bf16_f32 %0, %1, %2" : "=v"(r.u[1]) : "v"(a.z), "v"(a.w));
  asm("v_cvt_pk_bf16_f32 %0, %1, %2" : "=v"(r.u[2]) : "v"(b.x), "v"(b.y));
  asm("v_cvt_pk_bf16_f32 %0, %1, %2" : "=v"(r.u[3]) : "v"(b.z), "v"(b.w));
  return r.s;
}

// ------- Kernel A: per-block partials of ck[b][c], TRANSPOSED part (R8) ----
__global__ __launch_bounds__(256) void proj_kernel(const float* __restrict__ K,
                                                   const float* __restrict__ Wp,
                                                   float* __restrict__ part) {
  const float4* Wp4 = (const float4*)Wp;
  float acc[NB][NC];
#pragma unroll
  for (int b = 0; b < NB; ++b)
#pragma unroll
    for (int c = 0; c < NC; ++c) acc[b][c] = 0.f;

#pragma unroll
  for (int it = 0; it < 2; ++it) {
    int i4 = blockIdx.x * 512 + it * 256 + threadIdx.x;  // float4 idx over D_IN
    float w[20];
#pragma unroll
    for (int t = 0; t < 5; ++t) {
      float4 v = Wp4[i4 * 5 + t];
      w[4*t+0] = v.x; w[4*t+1] = v.y; w[4*t+2] = v.z; w[4*t+3] = v.w;
    }
#pragma unroll
    for (int b = 0; b < NB; ++b) {
      float4 kv = ((const float4*)(K + (size_t)b * D_IN))[i4];
      float ke[4] = {kv.x, kv.y, kv.z, kv.w};
#pragma unroll
      for (int e = 0; e < 4; ++e)
#pragma unroll
        for (int c = 0; c < NC; ++c)
          acc[b][c] = fmaf(ke[e], w[5*e + c], acc[b][c]);
    }
  }

  __shared__ float red[4][NB * NC];
  int wave = threadIdx.x >> 6;
  int lane = threadIdx.x & 63;
#pragma unroll
  for (int bc = 0; bc < NB * NC; ++bc) {
    float v = acc[bc / NC][bc % NC];
#pragma unroll
    for (int off = 32; off > 0; off >>= 1) v += __shfl_down(v, off);
    if (lane == 0) red[wave][bc] = v;
  }
  __syncthreads();
  if (threadIdx.x < NB * NC)
    part[threadIdx.x * PROJ_BLOCKS + blockIdx.x] =     // transposed
        red[0][threadIdx.x] + red[1][threadIdx.x] +
        red[2][threadIdx.x] + red[3][threadIdx.x];
}

// ---- Kernel B (fused): small-phase + 128q x (2 x 64k) score tiles ----
// R9: each block now serves TWO k-tiles (k in [kbase, kbase+128)): the staged
// Q, the qc results (k-independent) and the redundant small-phase are shared.
// K tile1 is prefetched to registers right after tile0 staging (HBM latency
// hides under small-phase + tile0 MFMA) and ds_written after tile0's reads
// drain. 1024 blocks = exactly 4/CU resident -> single dispatch round.
#define LDSTRIDE 72   // shorts; 144 B rows: 16B-aligned, uniform b128 bank spread
__global__ __launch_bounds__(256) void score_kernel(
    const float* __restrict__ Q, const float* __restrict__ K,
    const float* __restrict__ part, const float* __restrict__ bp,
    const float* __restrict__ Wq, const float* __restrict__ bq,
    const float* __restrict__ Wk, const float* __restrict__ bk,
    float* __restrict__ out) {
  __shared__ short Qs[128 * LDSTRIDE];       // 18432 B
  __shared__ short Ks[64 * LDSTRIDE];        //  9216 B
  __shared__ __align__(16) float sp[1280];   //  5120 B  => 32768 B total
  float* means_sh = sp;                      // [2][512]
  int*   inds_sh  = (int*)&sp[1024];         // 8
  float* cs4      = &sp[1032];               // [4][40]
  float* cq_sh    = &sp[1192];               // [8][5]
  float* ckk_sh   = &sp[1232];               // [8][5]
  float* ce_sh    = &sp[1272];               // 8

  const int bh    = blockIdx.x;
  const int qblk  = blockIdx.y << 7;         // 0,128,256,384
  const int kbase = blockIdx.z << 7;         // 0,128,256,384 (2 tiles of 64)
  const int h  = bh & 7;
  const int tid = threadIdx.x;
  const int w = tid >> 6, lane = tid & 63;
  const int lo5 = lane & 31, hi = lane >> 5;
  const int wq = w << 5;                     // wave's q offset in tile (0/32/64/96)

  const float* Qg = Q + (size_t)bh * (SEQ * DK) + (size_t)qblk * DK;
  const float* Kg = K + (size_t)bh * (SEQ * DK) + (size_t)kbase * DK;

  // ---- stage Q + K tile0 (fp32 -> bf16); loads issue before small-phase ----
#pragma unroll
  for (int i = 0; i < 4; ++i) {              // Q: 128 rows x 8 chunks
    int f8 = i * 256 + tid;
    int row = f8 >> 3, c8 = f8 & 7;
    const float4* qp = (const float4*)(Qg + row * DK + c8 * 8);
    *(short8*)&Qs[row * LDSTRIDE + c8 * 8] = pack8(qp[0], qp[1]);
  }
#pragma unroll
  for (int i = 0; i < 2; ++i) {              // K tile0: 64 rows x 8 chunks
    int f8 = i * 256 + tid;
    int row = f8 >> 3, c8 = f8 & 7;
    const float4* kp = (const float4*)(Kg + row * DK + c8 * 8);
    *(short8*)&Ks[row * LDSTRIDE + c8 * 8] = pack8(kp[0], kp[1]);
  }
  // ---- prefetch K tile1 to registers (raw fp32; packed at write time) ----
  float4 kpre[4];
#pragma unroll
  for (int i = 0; i < 2; ++i) {
    int f8 = i * 256 + tid;
    int row = f8 >> 3, c8 = f8 & 7;
    const float4* kp = (const float4*)(Kg + (64 + row) * DK + c8 * 8);
    kpre[2*i]   = kp[0];
    kpre[2*i+1] = kp[1];
  }

  // ---- small-phase: vectorized colsum (transposed part) -> softmax ----
  if (tid < 160) {
    int col = tid >> 2, sub = tid & 3;       // 40 cols x 4 threads
    const float4* p4 = (const float4*)part + col * 32 + sub * 8;
    float4 s4 = {0.f, 0.f, 0.f, 0.f};
#pragma unroll
    for (int i = 0; i < 8; ++i) {
      float4 v = p4[i];
      s4.x += v.x; s4.y += v.y; s4.z += v.z; s4.w += v.w;
    }
    cs4[sub * 40 + col] = (s4.x + s4.y) + (s4.z + s4.w);
  }
  __syncthreads();
  if (tid < 40)
    cs4[tid] = cs4[tid] + cs4[40 + tid] + cs4[80 + tid] + cs4[120 + tid];
  __syncthreads();
  if (tid < NB) {
    float cp[NC], zq[NC], zk[NC];
#pragma unroll
    for (int c = 0; c < NC; ++c) cp[c] = cs4[tid * NC + c] + bp[c];
#pragma unroll
    for (int c = 0; c < NC; ++c) { zq[c] = bq[c]; zk[c] = bk[c]; }
#pragma unroll
    for (int j = 0; j < NC; ++j)
#pragma unroll
      for (int c = 0; c < NC; ++c) {
        zq[c] = fmaf(cp[j], Wq[j * NC + c], zq[c]);
        zk[c] = fmaf(cp[j], Wk[j * NC + c], zk[c]);
      }
    float m = zq[0];
#pragma unroll
    for (int c = 1; c < NC; ++c) m = fmaxf(m, zq[c]);
    float e[NC], s = 0.f;
#pragma unroll
    for (int c = 0; c < NC; ++c) { e[c] = expf(zq[c] - m); s += e[c]; }
    float inv = 1.f / s;
    float p[NC];
#pragma unroll
    for (int c = 0; c < NC; ++c) { p[c] = e[c] * inv; cq_sh[tid * NC + c] = p[c]; }
    int am = 0; float bv = p[0];
#pragma unroll
    for (int c = 1; c < NC; ++c) if (p[c] > bv) { bv = p[c]; am = c; }
    inds_sh[tid] = am;
    float se = 0.f;
#pragma unroll
    for (int c = 0; c < NC; ++c) se += expf(p[c] - bv);
    float lse = bv + logf(se);
    float ceb = 0.f;
#pragma unroll
    for (int c = 0; c < NC; ++c) ceb -= p[c] * (p[c] - lse);
    ce_sh[tid] = ceb;
    m = zk[0];
#pragma unroll
    for (int c = 1; c < NC; ++c) m = fmaxf(m, zk[c]);
    s = 0.f;
#pragma unroll
    for (int c = 0; c < NC; ++c) { e[c] = expf(zk[c] - m); s += e[c]; }
    inv = 1.f / s;
#pragma unroll
    for (int c = 0; c < NC; ++c) ckk_sh[tid * NC + c] = e[c] * inv;
  }
  __syncthreads();

  // ---- loss: block (0,0,0) thread 0 only ----
  if (blockIdx.x == 0 && blockIdx.y == 0 && blockIdx.z == 0 && tid == 0) {
    float mu[NC];
#pragma unroll
    for (int c = 0; c < NC; ++c) {
      float sm = 0.f;
      for (int b = 0; b < NB; ++b) sm += cq_sh[b * NC + c];
      mu[c] = sm * 0.125f;
    }
    float loss_lp = 0.f;
#pragma unroll
    for (int c = 0; c < NC; ++c) {
      float sm = 0.f;
      for (int b = 0; b < NB; ++b) sm += ckk_sh[b * NC + c];
      float mk = sm * 0.125f;
      float var = 0.f;
      for (int b = 0; b < NB; ++b) {
        float d = ckk_sh[b * NC + c] - mk;
        var += d * d;
      }
      var *= (1.f / 7.f);                 // ddof=1
      float sd = sqrtf(var);
      float sigma = log1pf(expf(sd));     // softplus
      float ls = logf(sigma);
      for (int b = 0; b < NB; ++b) {
        float z = (ckk_sh[b * NC + c] - mu[c]) / sigma;
        loss_lp += -0.5f * z * z - ls - 0.91893853320467274f;
      }
    }
    float ce = 0.f;
    for (int b = 0; b < NB; ++b) ce += ce_sh[b];
    ce *= 0.125f;
    out[OUT_SCORE] = -(loss_lp / 40.f) + ce;
  }

  // ---- means slice: 1 float4/thread, 8 masked float4 accumulates (R8) ----
  const int cmin = (5 * h) >> 3;
  const int cmax = (5 * h + 4) >> 3;
  {
    int c2 = tid >> 7;                       // 0 or 1
    int c  = c2 ? cmax : cmin;
    int j4 = (tid & 127) << 2;               // j in steps of 4
    float4 sm = {0.f, 0.f, 0.f, 0.f};
#pragma unroll
    for (int b = 0; b < NB; ++b) {
      if (inds_sh[b] != c + 1) {
        float4 kv = *(const float4*)(K + (size_t)b * D_IN + j4);
        sm.x += kv.x; sm.y += kv.y; sm.z += kv.z; sm.w += kv.w;
      }
    }
    sm.x *= 0.125f; sm.y *= 0.125f; sm.z *= 0.125f; sm.w *= 0.125f;
    *(float4*)&means_sh[c2 * 512 + j4] = sm;
  }
  __syncthreads();

  // ---- means A-fragment (rows 0..7 = cmin, 8..15 = cmax, 16..31 zero) ----
  short8 mfrag[4];
#pragma unroll
  for (int s = 0; s < 4; ++s) {
    float4 a = {0.f, 0.f, 0.f, 0.f}, b = {0.f, 0.f, 0.f, 0.f};
    if (lo5 < 16) {
      const float* mp = means_sh + (lo5 >> 3 << 9) + (lo5 & 7) * 64 + s * 16 + hi * 8;
      a = *(const float4*)mp;
      b = *(const float4*)(mp + 4);
    }
    mfrag[s] = pack8(a, b);
  }

  __syncthreads();   // mfrag/means reads done; qcbuf may now overwrite sp

  f32x16 zero;
#pragma unroll
  for (int x = 0; x < 16; ++x) zero[x] = 0.f;

  // ---- MFMA tile0: 2 acc + 1 qc per k-step ----
  f32x16 acc0 = zero, acc1 = zero, aq = zero;
#pragma unroll
  for (int s = 0; s < 4; ++s) {
    int co = s * 16 + hi * 8;
    short8 a  = *(const short8*)&Qs[(wq + lo5)  * LDSTRIDE + co];
    short8 b0 = *(const short8*)&Ks[lo5         * LDSTRIDE + co];
    short8 b1 = *(const short8*)&Ks[(32 + lo5)  * LDSTRIDE + co];
    acc0 = __builtin_amdgcn_mfma_f32_32x32x16_bf16(a, b0, acc0, 0, 0, 0);
    acc1 = __builtin_amdgcn_mfma_f32_32x32x16_bf16(a, b1, acc1, 0, 0, 0);
    aq   = __builtin_amdgcn_mfma_f32_32x32x16_bf16(mfrag[s], a, aq, 0, 0, 0);
  }

  // ---- in-lane qc extraction -> wave-private LDS (no barrier needed) ----
  float* qcbuf = sp;
  {
    int qb = w * 320 + lo5 * 10 + 4 * hi;
    float2 p;
    p.x = fmaxf(aq[0], aq[4]) * 0.125f;
    p.y = fmaxf(aq[1], aq[5]) * 0.125f;
    *(float2*)&qcbuf[qb] = p;
    p.x = fmaxf(aq[2], aq[6]) * 0.125f;
    p.y = fmaxf(aq[3], aq[7]) * 0.125f;
    *(float2*)&qcbuf[qb + 2] = p;
  }

  // ---- epilogue tile0: qc from LDS (same-wave), plain scalar stores ----
  float* ob = out + (size_t)bh * (SEQ * SEQ);
  const int kc0 = kbase + lo5;
  const int r = lo5 & 7;
  const int qcb = w * 320 + r;
#pragma unroll
  for (int g = 0; g < 4; ++g) {
#pragma unroll
    for (int e = 0; e < 4; ++e) {
      int reg = 4 * g + e;
      int ql = e + 8 * g + 4 * hi;           // q within wave's 32-row window
      float qc = qcbuf[qcb + ql * 10];
      int qrow = qblk + wq + ql;
      ob[(size_t)qrow * SEQ + kc0]      = fmaxf(acc0[reg] * 0.125f, qc);
      ob[(size_t)qrow * SEQ + kc0 + 32] = fmaxf(acc1[reg] * 0.125f, qc);
    }
  }

  // ---- swap in K tile1 (all tile0 Ks reads drained by barrier) ----
  __syncthreads();
#pragma unroll
  for (int i = 0; i < 2; ++i) {
    int f8 = i * 256 + tid;
    int row = f8 >> 3, c8 = f8 & 7;
    *(short8*)&Ks[row * LDSTRIDE + c8 * 8] = pack8(kpre[2*i], kpre[2*i+1]);
  }
  __syncthreads();

  // ---- MFMA tile1 (no aq: qc is k-independent) + epilogue ----
  f32x16 acc0b = zero, acc1b = zero;
#pragma unroll
  for (int s = 0; s < 4; ++s) {
    int co = s * 16 + hi * 8;
    short8 a  = *(const short8*)&Qs[(wq + lo5)  * LDSTRIDE + co];
    short8 b0 = *(const short8*)&Ks[lo5         * LDSTRIDE + co];
    short8 b1 = *(const short8*)&Ks[(32 + lo5)  * LDSTRIDE + co];
    acc0b = __builtin_amdgcn_mfma_f32_32x32x16_bf16(a, b0, acc0b, 0, 0, 0);
    acc1b = __builtin_amdgcn_mfma_f32_32x32x16_bf16(a, b1, acc1b, 0, 0, 0);
  }
#pragma unroll
  for (int g = 0; g < 4; ++g) {
#pragma unroll
    for (int e = 0; e < 4; ++e) {
      int reg = 4 * g + e;
      int ql = e + 8 * g + 4 * hi;
      float qc = qcbuf[qcb + ql * 10];
      int qrow = qblk + wq + ql;
      ob[(size_t)qrow * SEQ + kc0 + 64] = fmaxf(acc0b[reg] * 0.125f, qc);
      ob[(size_t)qrow * SEQ + kc0 + 96] = fmaxf(acc1b[reg] * 0.125f, qc);
    }
  }
}

extern "C" void kernel_launch(void* const* d_in, const int* in_sizes, int n_in,
                              void* d_out, int out_size, void* d_ws, size_t ws_size,
                              hipStream_t stream) {
  const float* Q  = (const float*)d_in[0];
  const float* K  = (const float*)d_in[1];
  const float* Wp = (const float*)d_in[2];
  const float* bp = (const float*)d_in[3];
  const float* Wq = (const float*)d_in[4];
  const float* bq = (const float*)d_in[5];
  const float* Wk = (const float*)d_in[6];
  const float* bk = (const float*)d_in[7];
  float* out = (float*)d_out;

  float* part = (float*)d_ws;                      // 40 cols x 128 (transposed)

  proj_kernel<<<PROJ_BLOCKS, 256, 0, stream>>>(K, Wp, part);
  score_kernel<<<dim3(64, 4, 4), 256, 0, stream>>>(Q, K, part, bp, Wq, bq, Wk, bk, out);
}

// Round 10
// 119.116 us; speedup vs baseline: 1.1763x; 1.0038x over previous
//
#include <hip/hip_runtime.h>
#include <math.h>

#define NB 8
#define NH 8
#define SEQ 512
#define DK 64
#define NC 5
#define D_IN 262144   // 8*512*64 per batch
#define OUT_SCORE (NB*NH*SEQ*SEQ)   // 16777216
#define PROJ_BLOCKS 256

typedef short short8 __attribute__((ext_vector_type(8)));
typedef float f32x16 __attribute__((ext_vector_type(16)));

// fp32 -> bf16 via HW packed convert (RTNE, 1 instr per 2 elements). R7 win.
__device__ __forceinline__ short8 pack8(float4 a, float4 b) {
  union { short8 s; unsigned u[4]; } r;
  asm("v_cvt_pk_bf16_f32 %0, %1, %2" : "=v"(r.u[0]) : "v"(a.x), "v"(a.y));
  asm("v_cvt_pk_bf16_f32 %0, %1, %2" : "=v"(r.u[1]) : "v"(a.z), "v"(a.w));
  asm("v_cvt_pk_bf16_f32 %0, %1, %2" : "=v"(r.u[2]) : "v"(b.x), "v"(b.y));
  asm("v_cvt_pk_bf16_f32 %0, %1, %2" : "=v"(r.u[3]) : "v"(b.z), "v"(b.w));
  return r.s;
}

// ------- Kernel A: per-block partials of ck[b][c], TRANSPOSED part -------
// R10: 256 blocks (1 i4-iter each) instead of 128x2 — proj was latency-bound
// at 0.5 blocks/CU; doubling block count halves its serial depth.
__global__ __launch_bounds__(256) void proj_kernel(const float* __restrict__ K,
                                                   const float* __restrict__ Wp,
                                                   float* __restrict__ part) {
  const float4* Wp4 = (const float4*)Wp;
  float acc[NB][NC];
#pragma unroll
  for (int b = 0; b < NB; ++b)
#pragma unroll
    for (int c = 0; c < NC; ++c) acc[b][c] = 0.f;

  {
    int i4 = blockIdx.x * 256 + threadIdx.x;  // float4 idx over D_IN
    float w[20];
#pragma unroll
    for (int t = 0; t < 5; ++t) {
      float4 v = Wp4[i4 * 5 + t];
      w[4*t+0] = v.x; w[4*t+1] = v.y; w[4*t+2] = v.z; w[4*t+3] = v.w;
    }
#pragma unroll
    for (int b = 0; b < NB; ++b) {
      float4 kv = ((const float4*)(K + (size_t)b * D_IN))[i4];
      float ke[4] = {kv.x, kv.y, kv.z, kv.w};
#pragma unroll
      for (int e = 0; e < 4; ++e)
#pragma unroll
        for (int c = 0; c < NC; ++c)
          acc[b][c] = fmaf(ke[e], w[5*e + c], acc[b][c]);
    }
  }

  __shared__ float red[4][NB * NC];
  int wave = threadIdx.x >> 6;
  int lane = threadIdx.x & 63;
#pragma unroll
  for (int bc = 0; bc < NB * NC; ++bc) {
    float v = acc[bc / NC][bc % NC];
#pragma unroll
    for (int off = 32; off > 0; off >>= 1) v += __shfl_down(v, off);
    if (lane == 0) red[wave][bc] = v;
  }
  __syncthreads();
  if (threadIdx.x < NB * NC)
    part[threadIdx.x * PROJ_BLOCKS + blockIdx.x] =     // transposed
        red[0][threadIdx.x] + red[1][threadIdx.x] +
        red[2][threadIdx.x] + red[3][threadIdx.x];
}

// ---- Kernel B (fused): small-phase + 128q x (4 x 64k) score tiles ----
// R10: each block serves FOUR k-tiles (k in [kbase, kbase+256)) with rolling
// register prefetch (one tile ahead, 4xfloat4 = same VGPR cost as R9):
// write tile t to LDS, issue prefetch t+1, compute t — load latency hides
// under MFMA+stores of the previous tile. Q/qc/small-phase shared across 4.
// 512 blocks = 2/CU resident; no cross-block dependencies.
#define LDSTRIDE 72   // shorts; 144 B rows: 16B-aligned, uniform b128 bank spread
__global__ __launch_bounds__(256) void score_kernel(
    const float* __restrict__ Q, const float* __restrict__ K,
    const float* __restrict__ part, const float* __restrict__ bp,
    const float* __restrict__ Wq, const float* __restrict__ bq,
    const float* __restrict__ Wk, const float* __restrict__ bk,
    float* __restrict__ out) {
  __shared__ short Qs[128 * LDSTRIDE];       // 18432 B
  __shared__ short Ks[64 * LDSTRIDE];        //  9216 B
  __shared__ __align__(16) float sp[1280];   //  5120 B  => 32768 B total
  float* means_sh = sp;                      // [2][512]
  int*   inds_sh  = (int*)&sp[1024];         // 8
  float* cs4      = &sp[1032];               // [4][40]
  float* cq_sh    = &sp[1192];               // [8][5]
  float* ckk_sh   = &sp[1232];               // [8][5]
  float* ce_sh    = &sp[1272];               // 8

  const int bh    = blockIdx.x;
  const int qblk  = blockIdx.y << 7;         // 0,128,256,384
  const int kbase = blockIdx.z << 8;         // 0,256 (4 tiles of 64)
  const int h  = bh & 7;
  const int tid = threadIdx.x;
  const int w = tid >> 6, lane = tid & 63;
  const int lo5 = lane & 31, hi = lane >> 5;
  const int wq = w << 5;                     // wave's q offset in tile (0/32/64/96)

  const float* Qg = Q + (size_t)bh * (SEQ * DK) + (size_t)qblk * DK;
  const float* Kg = K + (size_t)bh * (SEQ * DK) + (size_t)kbase * DK;

  // ---- stage Q + K tile0 (fp32 -> bf16); loads issue before small-phase ----
#pragma unroll
  for (int i = 0; i < 4; ++i) {              // Q: 128 rows x 8 chunks
    int f8 = i * 256 + tid;
    int row = f8 >> 3, c8 = f8 & 7;
    const float4* qp = (const float4*)(Qg + row * DK + c8 * 8);
    *(short8*)&Qs[row * LDSTRIDE + c8 * 8] = pack8(qp[0], qp[1]);
  }
#pragma unroll
  for (int i = 0; i < 2; ++i) {              // K tile0: 64 rows x 8 chunks
    int f8 = i * 256 + tid;
    int row = f8 >> 3, c8 = f8 & 7;
    const float4* kp = (const float4*)(Kg + row * DK + c8 * 8);
    *(short8*)&Ks[row * LDSTRIDE + c8 * 8] = pack8(kp[0], kp[1]);
  }
  // ---- prefetch K tile1 to registers (raw fp32; packed at write time) ----
  float4 kpre[4];
#pragma unroll
  for (int i = 0; i < 2; ++i) {
    int f8 = i * 256 + tid;
    int row = f8 >> 3, c8 = f8 & 7;
    const float4* kp = (const float4*)(Kg + (size_t)(64 + row) * DK + c8 * 8);
    kpre[2*i]   = kp[0];
    kpre[2*i+1] = kp[1];
  }

  // ---- small-phase: vectorized colsum (transposed part, 256 rows) ----
  if (tid < 160) {
    int col = tid >> 2, sub = tid & 3;       // 40 cols x 4 threads
    const float4* p4 = (const float4*)part + col * 64 + sub * 16;
    float4 s4 = {0.f, 0.f, 0.f, 0.f};
#pragma unroll
    for (int i = 0; i < 16; ++i) {
      float4 v = p4[i];
      s4.x += v.x; s4.y += v.y; s4.z += v.z; s4.w += v.w;
    }
    cs4[sub * 40 + col] = (s4.x + s4.y) + (s4.z + s4.w);
  }
  __syncthreads();
  if (tid < 40)
    cs4[tid] = cs4[tid] + cs4[40 + tid] + cs4[80 + tid] + cs4[120 + tid];
  __syncthreads();
  if (tid < NB) {
    float cp[NC], zq[NC], zk[NC];
#pragma unroll
    for (int c = 0; c < NC; ++c) cp[c] = cs4[tid * NC + c] + bp[c];
#pragma unroll
    for (int c = 0; c < NC; ++c) { zq[c] = bq[c]; zk[c] = bk[c]; }
#pragma unroll
    for (int j = 0; j < NC; ++j)
#pragma unroll
      for (int c = 0; c < NC; ++c) {
        zq[c] = fmaf(cp[j], Wq[j * NC + c], zq[c]);
        zk[c] = fmaf(cp[j], Wk[j * NC + c], zk[c]);
      }
    float m = zq[0];
#pragma unroll
    for (int c = 1; c < NC; ++c) m = fmaxf(m, zq[c]);
    float e[NC], s = 0.f;
#pragma unroll
    for (int c = 0; c < NC; ++c) { e[c] = expf(zq[c] - m); s += e[c]; }
    float inv = 1.f / s;
    float p[NC];
#pragma unroll
    for (int c = 0; c < NC; ++c) { p[c] = e[c] * inv; cq_sh[tid * NC + c] = p[c]; }
    int am = 0; float bv = p[0];
#pragma unroll
    for (int c = 1; c < NC; ++c) if (p[c] > bv) { bv = p[c]; am = c; }
    inds_sh[tid] = am;
    float se = 0.f;
#pragma unroll
    for (int c = 0; c < NC; ++c) se += expf(p[c] - bv);
    float lse = bv + logf(se);
    float ceb = 0.f;
#pragma unroll
    for (int c = 0; c < NC; ++c) ceb -= p[c] * (p[c] - lse);
    ce_sh[tid] = ceb;
    m = zk[0];
#pragma unroll
    for (int c = 1; c < NC; ++c) m = fmaxf(m, zk[c]);
    s = 0.f;
#pragma unroll
    for (int c = 0; c < NC; ++c) { e[c] = expf(zk[c] - m); s += e[c]; }
    inv = 1.f / s;
#pragma unroll
    for (int c = 0; c < NC; ++c) ckk_sh[tid * NC + c] = e[c] * inv;
  }
  __syncthreads();

  // ---- loss: block (0,0,0) thread 0 only ----
  if (blockIdx.x == 0 && blockIdx.y == 0 && blockIdx.z == 0 && tid == 0) {
    float mu[NC];
#pragma unroll
    for (int c = 0; c < NC; ++c) {
      float sm = 0.f;
      for (int b = 0; b < NB; ++b) sm += cq_sh[b * NC + c];
      mu[c] = sm * 0.125f;
    }
    float loss_lp = 0.f;
#pragma unroll
    for (int c = 0; c < NC; ++c) {
      float sm = 0.f;
      for (int b = 0; b < NB; ++b) sm += ckk_sh[b * NC + c];
      float mk = sm * 0.125f;
      float var = 0.f;
      for (int b = 0; b < NB; ++b) {
        float d = ckk_sh[b * NC + c] - mk;
        var += d * d;
      }
      var *= (1.f / 7.f);                 // ddof=1
      float sd = sqrtf(var);
      float sigma = log1pf(expf(sd));     // softplus
      float ls = logf(sigma);
      for (int b = 0; b < NB; ++b) {
        float z = (ckk_sh[b * NC + c] - mu[c]) / sigma;
        loss_lp += -0.5f * z * z - ls - 0.91893853320467274f;
      }
    }
    float ce = 0.f;
    for (int b = 0; b < NB; ++b) ce += ce_sh[b];
    ce *= 0.125f;
    out[OUT_SCORE] = -(loss_lp / 40.f) + ce;
  }

  // ---- means slice: 1 float4/thread, 8 masked float4 accumulates (R8) ----
  const int cmin = (5 * h) >> 3;
  const int cmax = (5 * h + 4) >> 3;
  {
    int c2 = tid >> 7;                       // 0 or 1
    int c  = c2 ? cmax : cmin;
    int j4 = (tid & 127) << 2;               // j in steps of 4
    float4 sm = {0.f, 0.f, 0.f, 0.f};
#pragma unroll
    for (int b = 0; b < NB; ++b) {
      if (inds_sh[b] != c + 1) {
        float4 kv = *(const float4*)(K + (size_t)b * D_IN + j4);
        sm.x += kv.x; sm.y += kv.y; sm.z += kv.z; sm.w += kv.w;
      }
    }
    sm.x *= 0.125f; sm.y *= 0.125f; sm.z *= 0.125f; sm.w *= 0.125f;
    *(float4*)&means_sh[c2 * 512 + j4] = sm;
  }
  __syncthreads();

  // ---- means A-fragment (rows 0..7 = cmin, 8..15 = cmax, 16..31 zero) ----
  short8 mfrag[4];
#pragma unroll
  for (int s = 0; s < 4; ++s) {
    float4 a = {0.f, 0.f, 0.f, 0.f}, b = {0.f, 0.f, 0.f, 0.f};
    if (lo5 < 16) {
      const float* mp = means_sh + (lo5 >> 3 << 9) + (lo5 & 7) * 64 + s * 16 + hi * 8;
      a = *(const float4*)mp;
      b = *(const float4*)(mp + 4);
    }
    mfrag[s] = pack8(a, b);
  }

  __syncthreads();   // mfrag/means reads done; qcbuf may now overwrite sp

  f32x16 zero;
#pragma unroll
  for (int x = 0; x < 16; ++x) zero[x] = 0.f;

  // ---- MFMA tile0: 2 acc + 1 qc per k-step ----
  f32x16 acc0 = zero, acc1 = zero, aq = zero;
#pragma unroll
  for (int s = 0; s < 4; ++s) {
    int co = s * 16 + hi * 8;
    short8 a  = *(const short8*)&Qs[(wq + lo5)  * LDSTRIDE + co];
    short8 b0 = *(const short8*)&Ks[lo5         * LDSTRIDE + co];
    short8 b1 = *(const short8*)&Ks[(32 + lo5)  * LDSTRIDE + co];
    acc0 = __builtin_amdgcn_mfma_f32_32x32x16_bf16(a, b0, acc0, 0, 0, 0);
    acc1 = __builtin_amdgcn_mfma_f32_32x32x16_bf16(a, b1, acc1, 0, 0, 0);
    aq   = __builtin_amdgcn_mfma_f32_32x32x16_bf16(mfrag[s], a, aq, 0, 0, 0);
  }

  // ---- in-lane qc extraction -> wave-private LDS (no barrier needed) ----
  float* qcbuf = sp;
  {
    int qb = w * 320 + lo5 * 10 + 4 * hi;
    float2 p;
    p.x = fmaxf(aq[0], aq[4]) * 0.125f;
    p.y = fmaxf(aq[1], aq[5]) * 0.125f;
    *(float2*)&qcbuf[qb] = p;
    p.x = fmaxf(aq[2], aq[6]) * 0.125f;
    p.y = fmaxf(aq[3], aq[7]) * 0.125f;
    *(float2*)&qcbuf[qb + 2] = p;
  }

  // ---- epilogue tile0: qc from LDS (same-wave), plain scalar stores ----
  float* ob = out + (size_t)bh * (SEQ * SEQ);
  const int kc0 = kbase + lo5;
  const int r = lo5 & 7;
  const int qcb = w * 320 + r;
#pragma unroll
  for (int g = 0; g < 4; ++g) {
#pragma unroll
    for (int e = 0; e < 4; ++e) {
      int reg = 4 * g + e;
      int ql = e + 8 * g + 4 * hi;           // q within wave's 32-row window
      float qc = qcbuf[qcb + ql * 10];
      int qrow = qblk + wq + ql;
      ob[(size_t)qrow * SEQ + kc0]      = fmaxf(acc0[reg] * 0.125f, qc);
      ob[(size_t)qrow * SEQ + kc0 + 32] = fmaxf(acc1[reg] * 0.125f, qc);
    }
  }

  // ---- tiles 1..3: rolling prefetch (write kpre -> Ks, fetch next) ----
#pragma unroll
  for (int t = 1; t < 4; ++t) {
    __syncthreads();                         // all tile(t-1) Ks reads drained
#pragma unroll
    for (int i = 0; i < 2; ++i) {
      int f8 = i * 256 + tid;
      int row = f8 >> 3, c8 = f8 & 7;
      *(short8*)&Ks[row * LDSTRIDE + c8 * 8] = pack8(kpre[2*i], kpre[2*i+1]);
    }
    if (t < 3) {                             // prefetch tile t+1
#pragma unroll
      for (int i = 0; i < 2; ++i) {
        int f8 = i * 256 + tid;
        int row = f8 >> 3, c8 = f8 & 7;
        const float4* kp =
            (const float4*)(Kg + (size_t)(64 * (t + 1) + row) * DK + c8 * 8);
        kpre[2*i]   = kp[0];
        kpre[2*i+1] = kp[1];
      }
    }
    __syncthreads();

    f32x16 a0 = zero, a1 = zero;
#pragma unroll
    for (int s = 0; s < 4; ++s) {
      int co = s * 16 + hi * 8;
      short8 a  = *(const short8*)&Qs[(wq + lo5)  * LDSTRIDE + co];
      short8 b0 = *(const short8*)&Ks[lo5         * LDSTRIDE + co];
      short8 b1 = *(const short8*)&Ks[(32 + lo5)  * LDSTRIDE + co];
      a0 = __builtin_amdgcn_mfma_f32_32x32x16_bf16(a, b0, a0, 0, 0, 0);
      a1 = __builtin_amdgcn_mfma_f32_32x32x16_bf16(a, b1, a1, 0, 0, 0);
    }
#pragma unroll
    for (int g = 0; g < 4; ++g) {
#pragma unroll
      for (int e = 0; e < 4; ++e) {
        int reg = 4 * g + e;
        int ql = e + 8 * g + 4 * hi;
        float qc = qcbuf[qcb + ql * 10];
        int qrow = qblk + wq + ql;
        ob[(size_t)qrow * SEQ + kc0 + 64 * t]      = fmaxf(a0[reg] * 0.125f, qc);
        ob[(size_t)qrow * SEQ + kc0 + 64 * t + 32] = fmaxf(a1[reg] * 0.125f, qc);
      }
    }
  }
}

extern "C" void kernel_launch(void* const* d_in, const int* in_sizes, int n_in,
                              void* d_out, int out_size, void* d_ws, size_t ws_size,
                              hipStream_t stream) {
  const float* Q  = (const float*)d_in[0];
  const float* K  = (const float*)d_in[1];
  const float* Wp = (const float*)d_in[2];
  const float* bp = (const float*)d_in[3];
  const float* Wq = (const float*)d_in[4];
  const float* bq = (const float*)d_in[5];
  const float* Wk = (const float*)d_in[6];
  const float* bk = (const float*)d_in[7];
  float* out = (float*)d_out;

  float* part = (float*)d_ws;                      // 40 cols x 256 (transposed)

  proj_kernel<<<PROJ_BLOCKS, 256, 0, stream>>>(K, Wp, part);
  score_kernel<<<dim3(64, 4, 2), 256, 0, stream>>>(Q, K, part, bp, Wq, bq, Wk, bk, out);
}